// Round 10
// baseline (7858.283 us; speedup 1.0000x reference)
//
#include <hip/hip_runtime.h>
#include <hip/hip_cooperative_groups.h>
#include <math.h>

namespace cg = cooperative_groups;

// KMeansGrouping: B=32, N=4096, D=256, K=24, 25 iters.
// Round 10: single persistent cooperative kernel for the whole iteration loop
// (eliminates ~75 launch gaps + dispatch ramps, ~400-600us of r8's 1729us).
// Phase A reproduces r8's quarter-D f32 dot ordering EXACTLY (left-fold of 4
// 64-d partials) -> bit-identical argmins. Phase B = r8's ballot-compaction +
// indexed coalesced row loads, per 512-pt chunk. Phase C redistributes center
// updates over blocks. Cross-XCD coherence inside the persistent kernel:
// cT32/c_sq are write-once per iteration (26 buffers -> plain s_loads only hit
// cold K$/L2 lines, served fresh from L3); psums/cnts via agent-scope atomics
// (bypass non-coherent L2s). f64 trajectory state and summand sets unchanged;
// only f64 reassociation (class proven r4-r8). Fallback: r8 path on small ws
// or cooperative-launch error.

#define BATCH 32
#define NPTS 4096
#define DIM 256
#define NSLOT 24
#define NITER 25
// cooperative config
#define CB 256    // blocks (1/CU)
#define CHPTS 512 // points per block
#define NCHC 8    // chunks per batch
// r8 fallback config
#define QPTS 1024

#define ATOM_ST(p, v) __hip_atomic_store((p), (v), __ATOMIC_RELAXED, __HIP_MEMORY_SCOPE_AGENT)
#define ATOM_LD(p) __hip_atomic_load((p), __ATOMIC_RELAXED, __HIP_MEMORY_SCOPE_AGENT)

// ---------------- K0: per-point inverse norm (f64) ----------------
__global__ __launch_bounds__(256) void k_norm(const float* __restrict__ feat,
                                              double* __restrict__ inv_norm) {
  int lane = threadIdx.x & 63;
  int wid = threadIdx.x >> 6;
  int p = blockIdx.x * 4 + wid;
  const float4 v = *(const float4*)(feat + (size_t)p * DIM + lane * 4);
  double s = (double)v.x * v.x + (double)v.y * v.y + (double)v.z * v.z + (double)v.w * v.w;
#pragma unroll
  for (int m = 32; m; m >>= 1) s += __shfl_xor(s, m);
  if (lane == 0) inv_norm[p] = 1.0 / fmax(sqrt(s), 1e-12);
}

__device__ __forceinline__ double block_sum_256(double v, double* red) {
#pragma unroll
  for (int m = 32; m; m >>= 1) v += __shfl_xor(v, m);
  int w = threadIdx.x >> 6;
  if ((threadIdx.x & 63) == 0) red[w] = v;
  __syncthreads();
  return red[0] + red[1] + red[2] + red[3];
}

// ---------------- K0b: initial centers (f64 + f32 [d][k]) + c_sq32 --------
__global__ __launch_bounds__(256) void k_init_centers(const float* __restrict__ feat,
                                                      const double* __restrict__ inv_norm,
                                                      double* __restrict__ centers,
                                                      float* __restrict__ cT32,
                                                      float* __restrict__ c_sq32) {
  __shared__ double red[4];
  int t = threadIdx.x, k = blockIdx.x, b = blockIdx.y;
  int idx = (int)((double)k * (NPTS - 1) / (NSLOT - 1));
  double v = (double)feat[((size_t)b * NPTS + idx) * DIM + t] * inv_norm[b * NPTS + idx];
  centers[((size_t)b * NSLOT + k) * DIM + t] = v;
  cT32[((size_t)b * DIM + t) * NSLOT + k] = (float)v;
  double s = block_sum_256(v * v, red);
  if (t == 0) c_sq32[b * NSLOT + k] = (float)s;
}

// ---------------- K0c: tiled transpose feat -> xT[b][d][n] (f32) ----------
__global__ __launch_bounds__(256) void k_transpose(const float* __restrict__ feat,
                                                   float* __restrict__ xT) {
  __shared__ float tile[64][65];
  int ix = threadIdx.x & 63, iy = threadIdx.x >> 6;
  int bx = blockIdx.x, by = blockIdx.y, b = blockIdx.z;
  const float* fb = feat + ((size_t)b * NPTS + bx * 64) * DIM + by * 64;
#pragma unroll
  for (int r = 0; r < 64; r += 4)
    tile[r + iy][ix] = fb[(size_t)(r + iy) * DIM + ix];
  __syncthreads();
  float* xb = xT + ((size_t)b * DIM + by * 64) * NPTS + bx * 64;
#pragma unroll
  for (int r = 0; r < 64; r += 4)
    xb[(size_t)(r + iy) * NPTS + ix] = tile[ix][r + iy];
}

// ================= Cooperative persistent loop =================
__global__ __launch_bounds__(256) void k_loop(const float* __restrict__ feat,
                                              const float* __restrict__ xT,
                                              const double* __restrict__ inv_norm,
                                              float* __restrict__ cT_all,
                                              float* __restrict__ csq_all,
                                              double* __restrict__ centers,
                                              double* __restrict__ psumG,
                                              int* __restrict__ cntG,
                                              float* __restrict__ out_centers,
                                              float* __restrict__ out_masks) {
  cg::grid_group grid = cg::this_grid();
  __shared__ double i_lds[CHPTS];                 // 4 KB
  __shared__ int a_lds[CHPTS];                    // 2 KB
  __shared__ unsigned short list[CHPTS];          // 1 KB
  __shared__ int wcnt[8][NSLOT], goff[8][NSLOT];  // 1.5 KB
  __shared__ int off_lds[NSLOT], tot_lds[NSLOT];
  __shared__ double red[4];

  int blk = blockIdx.x;
  int ch = blk & 7;  // chunk within batch
  int b = blk >> 3;  // batch
  int t = threadIdx.x;
  int lane = t & 63;
  int w = __builtin_amdgcn_readfirstlane(t >> 6);

  i_lds[t] = inv_norm[b * NPTS + ch * CHPTS + t];
  i_lds[t + 256] = inv_norm[b * NPTS + ch * CHPTS + 256 + t];
  __syncthreads();

  int aH0 = 0, aH1 = 0;
  for (int it = 0; it <= NITER; ++it) {
    // ---- phase A: assignment, f32 scoring, EXACT r8 quarter-D order ----
    const float* cT = cT_all + (size_t)it * (BATCH * DIM * NSLOT) + (size_t)b * DIM * NSLOT;
    const float* csq = csq_all + (size_t)it * (BATCH * NSLOT) + b * NSLOT;
    for (int half = 0; half < 2; ++half) {
      int p = half * 256 + t;
      const float* xp = xT + (size_t)b * DIM * NPTS + (size_t)ch * CHPTS + p;
      float acc[NSLOT], cur[NSLOT];
#pragma unroll
      for (int k = 0; k < NSLOT; ++k) acc[k] = 0.0f;
      for (int q = 0; q < 4; ++q) { // quarter-D partials, left-folded (= r8)
#pragma unroll
        for (int k = 0; k < NSLOT; ++k) cur[k] = 0.0f;
        for (int d0 = q * 64; d0 < q * 64 + 64; d0 += 8) {
          float x[8];
#pragma unroll
          for (int j = 0; j < 8; ++j) x[j] = xp[(size_t)(d0 + j) * NPTS];
          const float* cp = cT + d0 * NSLOT; // block-uniform -> s_load
#pragma unroll
          for (int k = 0; k < NSLOT; ++k) {
            float s = cur[k];
#pragma unroll
            for (int j = 0; j < 8; ++j) s = fmaf(x[j], cp[j * NSLOT + k], s);
            cur[k] = s;
          }
        }
#pragma unroll
        for (int k = 0; k < NSLOT; ++k) acc[k] += cur[k];
      }
      float inv = (float)i_lds[p];
      int a = 0;
      float best = 0.0f;
#pragma unroll
      for (int k = 0; k < NSLOT; ++k) {
        float s = csq[k] - 2.0f * (acc[k] * inv);
        if (k == 0) { best = s; }
        else if (s < best) { best = s; a = k; } // strict < = first occurrence
      }
      a_lds[p] = a;
      if (half == 0) aH0 = a; else aH1 = a;
    }
    __syncthreads();
    if (it == NITER) break; // final assignment only

    // ---- sort: deterministic counting sort of 512 indices by cluster ----
    int aA = a_lds[w * 64 + lane];
    int aB = a_lds[256 + w * 64 + lane];
    for (int k = 0; k < NSLOT; ++k) {
      unsigned long long bA = __ballot(aA == k), bB = __ballot(aB == k);
      if (lane == 0) { wcnt[w][k] = __popcll(bA); wcnt[4 + w][k] = __popcll(bB); }
    }
    __syncthreads();
    if (t < NSLOT) {
      int s = 0;
#pragma unroll
      for (int g2 = 0; g2 < 8; ++g2) s += wcnt[g2][t];
      tot_lds[t] = s;
    }
    __syncthreads();
    if (t < NSLOT) {
      int off = 0;
      for (int k2 = 0; k2 < t; ++k2) off += tot_lds[k2];
      off_lds[t] = off;
      int base = off;
#pragma unroll
      for (int g2 = 0; g2 < 8; ++g2) { goff[g2][t] = base; base += wcnt[g2][t]; }
      ATOM_ST(&cntG[(b * NCHC + ch) * NSLOT + t], tot_lds[t]);
    }
    __syncthreads();
    unsigned long long lt = (1ull << lane) - 1ull;
    for (int k = 0; k < NSLOT; ++k) {
      unsigned long long bA = __ballot(aA == k);
      if (aA == k) list[goff[w][k] + __popcll(bA & lt)] = (unsigned short)(w * 64 + lane);
      unsigned long long bB = __ballot(aB == k);
      if (aB == k) list[goff[4 + w][k] + __popcll(bB & lt)] = (unsigned short)(256 + w * 64 + lane);
    }
    __syncthreads();

    // ---- phase B: per-wave cluster sums (ascending n), coalesced rows ----
    const float* fb = feat + ((size_t)b * NPTS + ch * CHPTS) * DIM + lane * 4;
    for (int kk = w; kk < NSLOT; kk += 4) {
      double a0 = 0.0, a1 = 0.0, a2 = 0.0, a3 = 0.0;
      int s0 = off_lds[kk], e0 = s0 + tot_lds[kk];
      for (int i = s0; i < e0; ++i) {
        int n = __builtin_amdgcn_readfirstlane((int)list[i]);
        float4 v = *(const float4*)(fb + (size_t)n * DIM);
        double iv = i_lds[n];
        a0 += (double)v.x * iv; a1 += (double)v.y * iv;
        a2 += (double)v.z * iv; a3 += (double)v.w * iv;
      }
      double* ps = psumG + ((size_t)(b * NCHC + ch) * NSLOT + kk) * DIM + lane * 4;
      ATOM_ST(ps + 0, a0); ATOM_ST(ps + 1, a1);
      ATOM_ST(ps + 2, a2); ATOM_ST(ps + 3, a3);
    }
    __threadfence();
    grid.sync();

    // ---- phase C: combine chunks -> centers + next cT32/c_sq ----
    for (int pp = 0; pp < 3; ++pp) {
      int pair = blk * 3 + pp; // 768 = 3*256 exactly
      int bb = pair / NSLOT, kc = pair % NSLOT;
      double s = 0.0; // ascending chunk order (deterministic)
#pragma unroll
      for (int c2 = 0; c2 < NCHC; ++c2)
        s += ATOM_LD(&psumG[((size_t)(bb * NCHC + c2) * NSLOT + kc) * DIM + t]);
      int cnt = 0;
#pragma unroll
      for (int c2 = 0; c2 < NCHC; ++c2)
        cnt += ATOM_LD(&cntG[(bb * NCHC + c2) * NSLOT + kc]);
      size_t ci = ((size_t)bb * NSLOT + kc) * DIM + t;
      double nc = (cnt > 0) ? (s / (double)cnt) : centers[ci];
      centers[ci] = nc; // block-private across iters (same block owns pair)
      ATOM_ST(&cT_all[(size_t)(it + 1) * (BATCH * DIM * NSLOT) +
                      ((size_t)bb * DIM + t) * NSLOT + kc], (float)nc);
      double sq = block_sum_256(nc * nc, red);
      if (t == 0)
        ATOM_ST(&csq_all[(size_t)(it + 1) * (BATCH * NSLOT) + bb * NSLOT + kc], (float)sq);
      __syncthreads(); // protect red[] reuse
    }
    __threadfence();
    grid.sync();
  }

  // ---- final outputs ----
#pragma unroll
  for (int k = 0; k < NSLOT; ++k) {
    out_masks[((size_t)b * NSLOT + k) * NPTS + ch * CHPTS + t] = (aH0 == k) ? 1.0f : 0.0f;
    out_masks[((size_t)b * NSLOT + k) * NPTS + ch * CHPTS + 256 + t] = (aH1 == k) ? 1.0f : 0.0f;
  }
  for (int pp = 0; pp < 3; ++pp) {
    int pair = blk * 3 + pp;
    int bb = pair / NSLOT, kc = pair % NSLOT;
    size_t ci = ((size_t)bb * NSLOT + kc) * DIM + t;
    out_centers[ci] = (float)centers[ci];
  }
}

// ================= r8 fallback kernels =================
template <bool USE_T>
__global__ __launch_bounds__(256) void k_assign(const float* __restrict__ feat,
                                                const float* __restrict__ xT,
                                                const double* __restrict__ inv_norm,
                                                const float* __restrict__ cT32,
                                                const float* __restrict__ c_sq32,
                                                int* __restrict__ assign) {
  __shared__ float part[3][64][NSLOT + 1];
  int lane = threadIdx.x & 63;
  int q = __builtin_amdgcn_readfirstlane(threadIdx.x >> 6);
  int blk = blockIdx.x, b = blockIdx.y;
  int n = blk * 64 + lane;
  const float* cb = cT32 + ((size_t)b * DIM + q * 64) * NSLOT;
  float dot[NSLOT];
#pragma unroll
  for (int k = 0; k < NSLOT; ++k) dot[k] = 0.0f;
  for (int d = 0; d < 64; d += 8) {
    float x[8];
    if (USE_T) {
      const float* xp = xT + ((size_t)b * DIM + q * 64 + d) * NPTS + n;
#pragma unroll
      for (int j = 0; j < 8; ++j) x[j] = xp[(size_t)j * NPTS];
    } else {
      float4 v = *(const float4*)(feat + ((size_t)b * NPTS + n) * DIM + q * 64 + d);
      float4 u = *(const float4*)(feat + ((size_t)b * NPTS + n) * DIM + q * 64 + d + 4);
      x[0] = v.x; x[1] = v.y; x[2] = v.z; x[3] = v.w;
      x[4] = u.x; x[5] = u.y; x[6] = u.z; x[7] = u.w;
    }
    const float* cp = cb + (size_t)d * NSLOT;
#pragma unroll
    for (int k = 0; k < NSLOT; ++k) {
      float s = dot[k];
#pragma unroll
      for (int j = 0; j < 8; ++j) s = fmaf(x[j], cp[j * NSLOT + k], s);
      dot[k] = s;
    }
  }
  if (q) {
#pragma unroll
    for (int k = 0; k < NSLOT; ++k) part[q - 1][lane][k] = dot[k];
  }
  __syncthreads();
  if (q == 0) {
    float inv = (float)inv_norm[b * NPTS + n];
    const float* csq = c_sq32 + b * NSLOT;
    int a = 0;
    float best = 0.0f;
#pragma unroll
    for (int k = 0; k < NSLOT; ++k) {
      float df = dot[k] + part[0][lane][k] + part[1][lane][k] + part[2][lane][k];
      float s = csq[k] - 2.0f * (df * inv);
      if (k == 0) { best = s; }
      else if (s < best) { best = s; a = k; }
    }
    assign[b * NPTS + n] = a;
  }
}

__global__ __launch_bounds__(256) void k_cluster4(const float* __restrict__ feat,
                                                  const double* __restrict__ inv_norm,
                                                  const int* __restrict__ assign,
                                                  double* __restrict__ psumG,
                                                  int* __restrict__ cntG) {
  __shared__ unsigned short list[QPTS];
  __shared__ int wtot[4];
  __shared__ double part[4][DIM];
  int id = blockIdx.x;
  int q = id & 3, r = id >> 2;
  int k = r % NSLOT, b = r / NSLOT;
  int t = threadIdx.x, lane = t & 63;
  int w = __builtin_amdgcn_readfirstlane(t >> 6);
  const int* ab = assign + b * NPTS + q * QPTS;
  int base = 0;
  for (int rr = 0; rr < QPTS / 256; ++rr) {
    bool m = (ab[rr * 256 + t] == k);
    unsigned long long bal = __ballot(m);
    int rank = __popcll(bal & ((1ull << lane) - 1ull));
    if (lane == 0) wtot[w] = __popcll(bal);
    __syncthreads();
    int off = base;
#pragma unroll
    for (int w2 = 0; w2 < 3; ++w2)
      if (w2 < w) off += wtot[w2];
    if (m) list[off + rank] = (unsigned short)(rr * 256 + t);
    base += wtot[0] + wtot[1] + wtot[2] + wtot[3];
    __syncthreads();
  }
  int mcount = base;
  const float* fb = feat + ((size_t)b * NPTS + q * QPTS) * DIM + lane * 4;
  const double* ib = inv_norm + b * NPTS + q * QPTS;
  double a0 = 0.0, a1 = 0.0, a2 = 0.0, a3 = 0.0;
  for (int i = w; i < mcount; i += 16) {
    bool h1 = (i + 4) < mcount, h2 = (i + 8) < mcount, h3 = (i + 12) < mcount;
    int n0 = __builtin_amdgcn_readfirstlane((int)list[i]);
    int n1 = __builtin_amdgcn_readfirstlane((int)list[h1 ? i + 4 : i]);
    int n2 = __builtin_amdgcn_readfirstlane((int)list[h2 ? i + 8 : i]);
    int n3 = __builtin_amdgcn_readfirstlane((int)list[h3 ? i + 12 : i]);
    float4 v0 = *(const float4*)(fb + (size_t)n0 * DIM);
    float4 v1 = *(const float4*)(fb + (size_t)n1 * DIM);
    float4 v2 = *(const float4*)(fb + (size_t)n2 * DIM);
    float4 v3 = *(const float4*)(fb + (size_t)n3 * DIM);
    double i0 = ib[n0], i1 = ib[n1], i2 = ib[n2], i3 = ib[n3];
    a0 += (double)v0.x * i0; a1 += (double)v0.y * i0;
    a2 += (double)v0.z * i0; a3 += (double)v0.w * i0;
    if (h1) { a0 += (double)v1.x * i1; a1 += (double)v1.y * i1;
              a2 += (double)v1.z * i1; a3 += (double)v1.w * i1; }
    if (h2) { a0 += (double)v2.x * i2; a1 += (double)v2.y * i2;
              a2 += (double)v2.z * i2; a3 += (double)v2.w * i2; }
    if (h3) { a0 += (double)v3.x * i3; a1 += (double)v3.y * i3;
              a2 += (double)v3.z * i3; a3 += (double)v3.w * i3; }
  }
  part[w][lane * 4 + 0] = a0;
  part[w][lane * 4 + 1] = a1;
  part[w][lane * 4 + 2] = a2;
  part[w][lane * 4 + 3] = a3;
  __syncthreads();
  double s = ((part[0][t] + part[1][t]) + part[2][t]) + part[3][t];
  psumG[(size_t)id * DIM + t] = s;
  if (t == 0) cntG[id] = mcount;
}

__global__ __launch_bounds__(256) void k_upd2(const double* __restrict__ psumG,
                                              const int* __restrict__ cntG,
                                              double* __restrict__ centers,
                                              float* __restrict__ cT32,
                                              float* __restrict__ c_sq32) {
  __shared__ double red[4];
  int t = threadIdx.x, k = blockIdx.x, b = blockIdx.y;
  int id = (b * NSLOT + k) * 4;
  const double* p = psumG + (size_t)id * DIM;
  double s = ((p[t] + p[DIM + t]) + p[2 * DIM + t]) + p[3 * DIM + t];
  int cnt = cntG[id] + cntG[id + 1] + cntG[id + 2] + cntG[id + 3];
  size_t ci = ((size_t)b * NSLOT + k) * DIM + t;
  double nc = (cnt > 0) ? (s / (double)cnt) : centers[ci];
  centers[ci] = nc;
  cT32[((size_t)b * DIM + t) * NSLOT + k] = (float)nc;
  double sq = block_sum_256(nc * nc, red);
  if (t == 0) c_sq32[b * NSLOT + k] = (float)sq;
}

__global__ __launch_bounds__(256) void k_mask(const int* __restrict__ assign,
                                              float* __restrict__ masks) {
  int t = threadIdx.x, nc = blockIdx.x, k = blockIdx.y, b = blockIdx.z;
  int n = nc * 256 + t;
  masks[((size_t)b * NSLOT + k) * NPTS + n] = (assign[b * NPTS + n] == k) ? 1.0f : 0.0f;
}

__global__ __launch_bounds__(256) void k_copyc(const double* __restrict__ centers,
                                               float* __restrict__ out_centers) {
  int t = threadIdx.x, k = blockIdx.x, b = blockIdx.y;
  size_t i = ((size_t)b * NSLOT + k) * DIM + t;
  out_centers[i] = (float)centers[i];
}

extern "C" void kernel_launch(void* const* d_in, const int* in_sizes, int n_in,
                              void* d_out, int out_size, void* d_ws, size_t ws_size,
                              hipStream_t stream) {
  (void)in_sizes; (void)n_in; (void)out_size;
  const float* feat = (const float*)d_in[0];
  float* out_centers = (float*)d_out;
  float* out_masks = out_centers + (size_t)BATCH * NSLOT * DIM;

  // layout: fallback-critical buffers first, 26-buffer tail last.
  char* p = (char*)d_ws;
  double* inv_norm = (double*)p; p += (size_t)BATCH * NPTS * 8;                   // 1.05 MB
  double* centers  = (double*)p; p += (size_t)BATCH * NSLOT * DIM * 8;            // 1.57 MB
  double* psumG    = (double*)p; p += (size_t)BATCH * NCHC * NSLOT * DIM * 8;     // 12.58 MB
  int* cntG        = (int*)p;    p += (size_t)BATCH * NCHC * NSLOT * 4;           // 24.6 KB
  float* xT        = (float*)p;  p += (size_t)BATCH * DIM * NPTS * 4;             // 134.2 MB
  float* cT_all    = (float*)p;  p += (size_t)(NITER + 1) * BATCH * DIM * NSLOT * 4; // 20.4 MB
  float* csq_all   = (float*)p;  p += (size_t)(NITER + 1) * BATCH * NSLOT * 4;    // 80 KB
  size_t need_coop = (size_t)(p - (char*)d_ws);
  size_t need_fb = (size_t)((char*)cT_all - (char*)d_ws) +
                   (size_t)BATCH * DIM * NSLOT * 4 + (size_t)BATCH * NSLOT * 4;
  bool coop = ws_size >= need_coop;
  bool fb_xT = ws_size >= need_fb;

  k_norm<<<BATCH * NPTS / 4, 256, 0, stream>>>(feat, inv_norm);
  k_init_centers<<<dim3(NSLOT, BATCH), 256, 0, stream>>>(feat, inv_norm, centers,
                                                         cT_all, csq_all);
  if (coop || fb_xT)
    k_transpose<<<dim3(NPTS / 64, DIM / 64, BATCH), 256, 0, stream>>>(feat, xT);

  if (coop) {
    const float* feat_ = feat; const float* xT_ = xT; const double* inv_ = inv_norm;
    float* cT_ = cT_all; float* csq_ = csq_all; double* cen_ = centers;
    double* ps_ = psumG; int* cg_ = cntG;
    float* oc_ = out_centers; float* om_ = out_masks;
    void* args[] = {&feat_, &xT_, &inv_, &cT_, &csq_, &cen_, &ps_, &cg_, &oc_, &om_};
    hipError_t e = hipLaunchCooperativeKernel((const void*)k_loop, dim3(CB), dim3(256),
                                              args, 0, stream);
    if (e == hipSuccess) return;
  }

  // ---- r8 fallback (proven 1729us) ----
  float* cT32 = cT_all;        // buffer 0
  float* c_sq32 = csq_all;     // buffer 0
  int* assign = (int*)(psumG + (size_t)BATCH * NSLOT * 4 * DIM); // after r8 psum region
  for (int it = 0; it <= NITER; ++it) {
    if (fb_xT)
      k_assign<true><<<dim3(NPTS / 64, BATCH), 256, 0, stream>>>(feat, xT, inv_norm,
                                                                 cT32, c_sq32, assign);
    else
      k_assign<false><<<dim3(NPTS / 64, BATCH), 256, 0, stream>>>(feat, xT, inv_norm,
                                                                  cT32, c_sq32, assign);
    if (it == NITER) break;
    k_cluster4<<<NSLOT * BATCH * 4, 256, 0, stream>>>(feat, inv_norm, assign,
                                                      psumG, cntG);
    k_upd2<<<dim3(NSLOT, BATCH), 256, 0, stream>>>(psumG, cntG, centers, cT32, c_sq32);
  }
  k_mask<<<dim3(NPTS / 256, NSLOT, BATCH), 256, 0, stream>>>(assign, out_masks);
  k_copyc<<<dim3(NSLOT, BATCH), 256, 0, stream>>>(centers, out_centers);
}

// Round 11
// 2666.386 us; speedup vs baseline: 2.9472x; 2.9472x over previous
//
#include <hip/hip_runtime.h>
#include <math.h>

// KMeansGrouping: B=32, N=4096, D=256, K=24, 25 iters.
// Round 11: fused assign+sort+sum kernel (one per iteration, 512 blocks x 256
// pts = 2/CU, 8 waves/CU). Phase A = r10's VERIFIED thread-per-point quarter-D
// f32 scoring from xT (bit-identical argmins to r8). Sort = r10's verified
// ballot-prefix counting sort in LDS. Phase B = sorted-run accumulation:
// thread t owns dim t; stream this block's 256 feat rows in sorted-by-cluster
// order (coalesced 1KB row reads, 8 in flight); ONE f64 accumulator; flush to
// psumG at cluster boundaries (each cluster = one contiguous run). No 24-bucket
// register spill (r4/r5/r8 lesson), no LDS rmw (r9 lesson), no persistent
// kernel (r10 lesson). k_upd3 = r5's proven 16-chunk ascending combine + exact
// int counts. f64 trajectory unchanged; reassociation-only deltas (r4-r10 class).

#define BATCH 32
#define NPTS 4096
#define DIM 256
#define NSLOT 24
#define NITER 25
#define NCH 16
#define CPTS 256 // points per fused block

// ---------------- K0: per-point inverse norm (f64) ----------------
__global__ __launch_bounds__(256) void k_norm(const float* __restrict__ feat,
                                              double* __restrict__ inv_norm) {
  int lane = threadIdx.x & 63;
  int wid = threadIdx.x >> 6;
  int p = blockIdx.x * 4 + wid;
  const float4 v = *(const float4*)(feat + (size_t)p * DIM + lane * 4);
  double s = (double)v.x * v.x + (double)v.y * v.y + (double)v.z * v.z + (double)v.w * v.w;
#pragma unroll
  for (int m = 32; m; m >>= 1) s += __shfl_xor(s, m);
  if (lane == 0) inv_norm[p] = 1.0 / fmax(sqrt(s), 1e-12);
}

__device__ __forceinline__ double block_sum_256(double v, double* red) {
#pragma unroll
  for (int m = 32; m; m >>= 1) v += __shfl_xor(v, m);
  int w = threadIdx.x >> 6;
  if ((threadIdx.x & 63) == 0) red[w] = v;
  __syncthreads();
  return red[0] + red[1] + red[2] + red[3];
}

// ---------------- K0b: initial centers (f64 + f32 [d][k]) + c_sq32 --------
// init_idx = floor(linspace(0, N-1, K)): idx_k = floor(k*4095/23).
__global__ __launch_bounds__(256) void k_init_centers(const float* __restrict__ feat,
                                                      const double* __restrict__ inv_norm,
                                                      double* __restrict__ centers,
                                                      float* __restrict__ cT32,
                                                      float* __restrict__ c_sq32) {
  __shared__ double red[4];
  int t = threadIdx.x, k = blockIdx.x, b = blockIdx.y;
  int idx = (int)((double)k * (NPTS - 1) / (NSLOT - 1));
  double v = (double)feat[((size_t)b * NPTS + idx) * DIM + t] * inv_norm[b * NPTS + idx];
  centers[((size_t)b * NSLOT + k) * DIM + t] = v;
  cT32[((size_t)b * DIM + t) * NSLOT + k] = (float)v;
  double s = block_sum_256(v * v, red);
  if (t == 0) c_sq32[b * NSLOT + k] = (float)s;
}

// ---------------- K0c: tiled transpose feat -> xT[b][d][n] (f32) ----------
__global__ __launch_bounds__(256) void k_transpose(const float* __restrict__ feat,
                                                   float* __restrict__ xT) {
  __shared__ float tile[64][65];
  int ix = threadIdx.x & 63, iy = threadIdx.x >> 6;
  int bx = blockIdx.x, by = blockIdx.y, b = blockIdx.z;
  const float* fb = feat + ((size_t)b * NPTS + bx * 64) * DIM + by * 64;
#pragma unroll
  for (int r = 0; r < 64; r += 4)
    tile[r + iy][ix] = fb[(size_t)(r + iy) * DIM + ix];
  __syncthreads();
  float* xb = xT + ((size_t)b * DIM + by * 64) * NPTS + bx * 64;
#pragma unroll
  for (int r = 0; r < 64; r += 4)
    xb[(size_t)(r + iy) * NPTS + ix] = tile[ix][r + iy];
}

// ---------------- K1: fused assign + sort + cluster-run sums ----------------
template <bool USE_T, bool FINAL>
__global__ __launch_bounds__(256) void k_fused(const float* __restrict__ feat,
                                               const float* __restrict__ xT,
                                               const double* __restrict__ inv_norm,
                                               const float* __restrict__ cT32,
                                               const float* __restrict__ c_sq32,
                                               double* __restrict__ psumG,
                                               int* __restrict__ cntG,
                                               float* __restrict__ masks) {
  __shared__ double i_lds[CPTS];                   // 2 KB
  __shared__ int a_lds[CPTS];                      // 1 KB
  __shared__ unsigned short list[CPTS];            // 0.5 KB
  __shared__ unsigned char sk_arr[CPTS];           // 0.25 KB
  __shared__ int wcnt[4][NSLOT], goff[4][NSLOT];   // 768 B
  __shared__ int off_lds[NSLOT], tot_lds[NSLOT];   // 192 B
  int ch = blockIdx.x, b = blockIdx.y;
  int t = threadIdx.x;
  int lane = t & 63;
  int w = __builtin_amdgcn_readfirstlane(t >> 6);

  i_lds[t] = inv_norm[b * NPTS + ch * CPTS + t];
  __syncthreads();

  // ---- phase A: f32 scoring, EXACT r8/r10 quarter-D left-fold order ----
  const float* cT = cT32 + (size_t)b * DIM * NSLOT;
  const float* csq = c_sq32 + b * NSLOT;
  float acc[NSLOT], cur[NSLOT];
#pragma unroll
  for (int k = 0; k < NSLOT; ++k) acc[k] = 0.0f;
  const float* xp = USE_T ? (xT + (size_t)b * DIM * NPTS + ch * CPTS + t)
                          : (feat + ((size_t)b * NPTS + ch * CPTS + t) * DIM);
  for (int q = 0; q < 4; ++q) { // quarter-D partials, left-folded (= r8)
#pragma unroll
    for (int k = 0; k < NSLOT; ++k) cur[k] = 0.0f;
    for (int d0 = q * 64; d0 < q * 64 + 64; d0 += 8) {
      float x[8];
      if (USE_T) {
#pragma unroll
        for (int j = 0; j < 8; ++j) x[j] = xp[(size_t)(d0 + j) * NPTS];
      } else {
        float4 v = *(const float4*)(xp + d0);
        float4 u = *(const float4*)(xp + d0 + 4);
        x[0] = v.x; x[1] = v.y; x[2] = v.z; x[3] = v.w;
        x[4] = u.x; x[5] = u.y; x[6] = u.z; x[7] = u.w;
      }
      const float* cp = cT + d0 * NSLOT; // block-uniform -> s_load
#pragma unroll
      for (int k = 0; k < NSLOT; ++k) {
        float s = cur[k];
#pragma unroll
        for (int j = 0; j < 8; ++j) s = fmaf(x[j], cp[j * NSLOT + k], s);
        cur[k] = s;
      }
    }
#pragma unroll
    for (int k = 0; k < NSLOT; ++k) acc[k] += cur[k];
  }
  float inv = (float)i_lds[t];
  int a = 0;
  float best = 0.0f;
#pragma unroll
  for (int k = 0; k < NSLOT; ++k) {
    float s = csq[k] - 2.0f * (acc[k] * inv);
    if (k == 0) { best = s; }
    else if (s < best) { best = s; a = k; } // strict < = first occurrence
  }

  if (FINAL) { // write masks directly, done
#pragma unroll
    for (int k = 0; k < NSLOT; ++k)
      masks[((size_t)b * NSLOT + k) * NPTS + ch * CPTS + t] = (a == k) ? 1.0f : 0.0f;
    return;
  }
  a_lds[t] = a;
  __syncthreads();

  // ---- counting sort (ballot-prefix, ascending n within cluster) ----
  for (int k = 0; k < NSLOT; ++k) {
    unsigned long long bal = __ballot(a == k);
    if (lane == 0) wcnt[w][k] = __popcll(bal);
  }
  __syncthreads();
  if (t < NSLOT) {
    tot_lds[t] = wcnt[0][t] + wcnt[1][t] + wcnt[2][t] + wcnt[3][t];
  }
  __syncthreads();
  if (t < NSLOT) {
    int off = 0;
    for (int k2 = 0; k2 < t; ++k2) off += tot_lds[k2];
    off_lds[t] = off;
    int base = off;
#pragma unroll
    for (int g = 0; g < 4; ++g) { goff[g][t] = base; base += wcnt[g][t]; }
    cntG[(b * NCH + ch) * NSLOT + t] = tot_lds[t];
  }
  __syncthreads();
  unsigned long long lt = (1ull << lane) - 1ull;
  for (int k = 0; k < NSLOT; ++k) {
    unsigned long long bal = __ballot(a == k);
    if (a == k) {
      int pos = goff[w][k] + __popcll(bal & lt);
      list[pos] = (unsigned short)t;
      sk_arr[pos] = (unsigned char)k;
    }
  }
  __syncthreads();

  // ---- phase B: sorted-run accumulation, thread t = dim t ----
  const float* fb = feat + ((size_t)b * NPTS + ch * CPTS) * DIM + t;
  double* psB = psumG + (size_t)(b * NCH + ch) * NSLOT * DIM + t;
  double racc = 0.0;
  for (int i0 = 0; i0 < CPTS; i0 += 8) {
    int nn[8];
    float x[8];
#pragma unroll
    for (int j = 0; j < 8; ++j)
      nn[j] = __builtin_amdgcn_readfirstlane((int)list[i0 + j]);
#pragma unroll
    for (int j = 0; j < 8; ++j) x[j] = fb[(size_t)nn[j] * DIM]; // 8 rows in flight
#pragma unroll
    for (int j = 0; j < 8; ++j) {
      int i = i0 + j;
      racc += (double)x[j] * i_lds[nn[j]];
      int kcur = __builtin_amdgcn_readfirstlane((int)sk_arr[i]); // uniform
      int knxt = (i < CPTS - 1) ? __builtin_amdgcn_readfirstlane((int)sk_arr[i + 1]) : -1;
      if (kcur != knxt) { // cluster run ends -> single flush
        psB[(size_t)kcur * DIM] = racc;
        racc = 0.0;
      }
    }
  }
  // zero-fill empty clusters (each slot written exactly once per block)
  for (int k = 0; k < NSLOT; ++k)
    if (tot_lds[k] == 0) psB[(size_t)k * DIM] = 0.0;
}

// ---------------- K2: combine 16 chunks -> new centers + cT32 + c_sq ------
__global__ __launch_bounds__(256) void k_upd3(const double* __restrict__ psumG,
                                              const int* __restrict__ cntG,
                                              double* __restrict__ centers,
                                              float* __restrict__ cT32,
                                              float* __restrict__ c_sq32) {
  __shared__ double red[4];
  int t = threadIdx.x, k = blockIdx.x, b = blockIdx.y;
  double s = 0.0; // fixed ascending chunk order (deterministic)
#pragma unroll
  for (int ch = 0; ch < NCH; ++ch)
    s += psumG[((size_t)(b * NCH + ch) * NSLOT + k) * DIM + t];
  int cnt = 0;
#pragma unroll
  for (int ch = 0; ch < NCH; ++ch)
    cnt += cntG[(b * NCH + ch) * NSLOT + k];

  size_t ci = ((size_t)b * NSLOT + k) * DIM + t;
  double nc = (cnt > 0) ? (s / (double)cnt) : centers[ci];
  centers[ci] = nc;
  cT32[((size_t)b * DIM + t) * NSLOT + k] = (float)nc;
  double sq = block_sum_256(nc * nc, red);
  if (t == 0) c_sq32[b * NSLOT + k] = (float)sq;
}

// ---------------- K3: centers output ----------------
__global__ __launch_bounds__(256) void k_copyc(const double* __restrict__ centers,
                                               float* __restrict__ out_centers) {
  int t = threadIdx.x, k = blockIdx.x, b = blockIdx.y;
  size_t i = ((size_t)b * NSLOT + k) * DIM + t;
  out_centers[i] = (float)centers[i];
}

extern "C" void kernel_launch(void* const* d_in, const int* in_sizes, int n_in,
                              void* d_out, int out_size, void* d_ws, size_t ws_size,
                              hipStream_t stream) {
  (void)in_sizes; (void)n_in; (void)out_size;
  const float* feat = (const float*)d_in[0];
  float* out_centers = (float*)d_out;                           // (32,24,256)
  float* out_masks = out_centers + (size_t)BATCH * NSLOT * DIM; // (32,24,4096)

  // workspace: ~29 MB fixed + 134 MB xT tail (optional).
  char* p = (char*)d_ws;
  double* inv_norm = (double*)p; p += (size_t)BATCH * NPTS * 8;              // 1.05 MB
  double* centers  = (double*)p; p += (size_t)BATCH * NSLOT * DIM * 8;       // 1.57 MB
  float* cT32      = (float*)p;  p += (size_t)BATCH * DIM * NSLOT * 4;       // 0.79 MB
  float* c_sq32    = (float*)p;  p += (size_t)BATCH * NSLOT * 4;             // 3 KB
  double* psumG    = (double*)p; p += (size_t)BATCH * NCH * NSLOT * DIM * 8; // 25.2 MB
  int* cntG        = (int*)p;    p += (size_t)BATCH * NCH * NSLOT * 4;       // 49 KB
  float* xT        = (float*)p;
  size_t need_xT = (size_t)(p - (char*)d_ws) + (size_t)BATCH * DIM * NPTS * 4; // ~163 MB
  bool useT = ws_size >= need_xT;

  k_norm<<<BATCH * NPTS / 4, 256, 0, stream>>>(feat, inv_norm);
  k_init_centers<<<dim3(NSLOT, BATCH), 256, 0, stream>>>(feat, inv_norm, centers,
                                                         cT32, c_sq32);
  if (useT)
    k_transpose<<<dim3(NPTS / 64, DIM / 64, BATCH), 256, 0, stream>>>(feat, xT);

  dim3 fg(NCH, BATCH);
  for (int it = 0; it < NITER; ++it) {
    if (useT)
      k_fused<true, false><<<fg, 256, 0, stream>>>(feat, xT, inv_norm, cT32, c_sq32,
                                                   psumG, cntG, out_masks);
    else
      k_fused<false, false><<<fg, 256, 0, stream>>>(feat, xT, inv_norm, cT32, c_sq32,
                                                    psumG, cntG, out_masks);
    k_upd3<<<dim3(NSLOT, BATCH), 256, 0, stream>>>(psumG, cntG, centers, cT32, c_sq32);
  }
  if (useT)
    k_fused<true, true><<<fg, 256, 0, stream>>>(feat, xT, inv_norm, cT32, c_sq32,
                                                psumG, cntG, out_masks);
  else
    k_fused<false, true><<<fg, 256, 0, stream>>>(feat, xT, inv_norm, cT32, c_sq32,
                                                 psumG, cntG, out_masks);
  k_copyc<<<dim3(NSLOT, BATCH), 256, 0, stream>>>(centers, out_centers);
}